// Round 2
// baseline (4794.991 us; speedup 1.0000x reference)
//
#include <hip/hip_runtime.h>

typedef unsigned int uint;

enum { ACT_RELU=0, ACT_SIGMOID=1, ACT_RESBN=2 };

// ---------------- fused GEMM (f32): C = act(A @ W + bias) [+BN/residual] -----
// A:[M,K] row-major, W:[K,N] row-major. Optional second store C2 (same values).
// tile 64x64, BK=16, 256 threads, 4x4 acc/thread. M%64==0, K%16==0.
template<int ACT>
__global__ __launch_bounds__(256) void gemm_fused(
    const float* __restrict__ A, const float* __restrict__ W,
    const float* __restrict__ bias, float* __restrict__ C,
    float* __restrict__ C2, const float* __restrict__ R,
    const float* __restrict__ gamma, const float* __restrict__ beta,
    int M, int N, int K)
{
    __shared__ float As[16][68];
    __shared__ float Bs[16][68];
    const int tx = threadIdx.x, ty = threadIdx.y;
    const int tid = ty*16 + tx;
    const int row0 = blockIdx.y*64, col0 = blockIdx.x*64;
    float acc[4][4] = {};
    for (int k0 = 0; k0 < K; k0 += 16) {
        #pragma unroll
        for (int t = tid; t < 1024; t += 256) {
            int r = t >> 4, c = t & 15;
            As[c][r] = A[(size_t)(row0+r)*K + k0 + c];
        }
        #pragma unroll
        for (int t = tid; t < 1024; t += 256) {
            int kr = t >> 6, c = t & 63;
            int gc = col0 + c;
            Bs[kr][c] = (gc < N) ? W[(size_t)(k0+kr)*N + gc] : 0.f;
        }
        __syncthreads();
        #pragma unroll
        for (int kk = 0; kk < 16; kk++) {
            float a[4], b[4];
            #pragma unroll
            for (int i = 0; i < 4; i++) a[i] = As[kk][ty*4+i];
            #pragma unroll
            for (int j = 0; j < 4; j++) b[j] = Bs[kk][tx*4+j];
            #pragma unroll
            for (int i = 0; i < 4; i++)
                #pragma unroll
                for (int j = 0; j < 4; j++)
                    acc[i][j] += a[i]*b[j];
        }
        __syncthreads();
    }
    const float INVS = 0.99999500003749968f; // 1/sqrt(1+1e-5)
    #pragma unroll
    for (int i = 0; i < 4; i++) {
        int r = row0 + ty*4 + i;
        #pragma unroll
        for (int j = 0; j < 4; j++) {
            int c = col0 + tx*4 + j;
            if (c < N) {
                float v = acc[i][j] + bias[c];
                if (ACT == ACT_RELU) {
                    v = fmaxf(v, 0.f);
                } else if (ACT == ACT_SIGMOID) {
                    v = 1.f/(1.f + expf(-v));
                } else { // RESBN: relu -> *gamma/sqrt(1+eps)+beta -> +R
                    v = fmaxf(v, 0.f);
                    v = v*(gamma[c]*INVS) + beta[c];
                    v += R[(size_t)r*N + c];
                }
                C[(size_t)r*N + c] = v;
                if (C2) C2[(size_t)r*N + c] = v;
            }
        }
    }
}

// ---------------- split-K accumulating GEMM: C += A@W chunk ------------------
__global__ __launch_bounds__(256) void gemm_acc(
    const float* __restrict__ A, const float* __restrict__ W,
    float* __restrict__ C, int M, int N, int K, int kchunk)
{
    __shared__ float As[16][68];
    __shared__ float Bs[16][68];
    const int tx = threadIdx.x, ty = threadIdx.y;
    const int tid = ty*16 + tx;
    const int row0 = blockIdx.y*64, col0 = blockIdx.x*64;
    const int kbeg = blockIdx.z * kchunk, kend = kbeg + kchunk;
    float acc[4][4] = {};
    for (int k0 = kbeg; k0 < kend; k0 += 16) {
        #pragma unroll
        for (int t = tid; t < 1024; t += 256) {
            int r = t >> 4, c = t & 15;
            As[c][r] = A[(size_t)(row0+r)*K + k0 + c];
        }
        #pragma unroll
        for (int t = tid; t < 1024; t += 256) {
            int kr = t >> 6, c = t & 63;
            int gc = col0 + c;
            Bs[kr][c] = (gc < N) ? W[(size_t)(k0+kr)*N + gc] : 0.f;
        }
        __syncthreads();
        #pragma unroll
        for (int kk = 0; kk < 16; kk++) {
            float a[4], b[4];
            #pragma unroll
            for (int i = 0; i < 4; i++) a[i] = As[kk][ty*4+i];
            #pragma unroll
            for (int j = 0; j < 4; j++) b[j] = Bs[kk][tx*4+j];
            #pragma unroll
            for (int i = 0; i < 4; i++)
                #pragma unroll
                for (int j = 0; j < 4; j++)
                    acc[i][j] += a[i]*b[j];
        }
        __syncthreads();
    }
    #pragma unroll
    for (int i = 0; i < 4; i++) {
        int r = row0 + ty*4 + i;
        #pragma unroll
        for (int j = 0; j < 4; j++) {
            int c = col0 + tx*4 + j;
            if (c < N) atomicAdd(&C[(size_t)r*N + c], acc[i][j]);
        }
    }
}

// ---------------- epilogue for split-K results -------------------------------
template<int ACT>
__global__ __launch_bounds__(256) void epi_k(
    float* __restrict__ C, const float* __restrict__ bias,
    float* __restrict__ dst, int M, int N)
{
    int i = blockIdx.x*256 + threadIdx.x;
    if (i >= M*N) return;
    int c = i % N;
    float v = C[i] + bias[c];
    if (ACT == ACT_RELU) v = fmaxf(v, 0.f);
    else v = 1.f/(1.f + expf(-v));
    C[i] = v;
    if (dst) dst[i] = v;
}

__global__ __launch_bounds__(256) void zero_k(float* __restrict__ p, int n)
{
    int i = blockIdx.x*256 + threadIdx.x;
    if (i < n) p[i] = 0.f;
}

// ---------------- Esq: per-code squared norms (bitwise-same accum order) -----
__global__ __launch_bounds__(256) void esq_k(
    const float* __restrict__ E, float* __restrict__ Esq)
{
    int k = blockIdx.x*256 + threadIdx.x;
    if (k >= 512) return;
    const float4* row = (const float4*)(E + (size_t)k*64);
    float s = 0.f;
    #pragma unroll
    for (int m = 0; m < 16; m++) {
        float4 w = row[m];
        s += w.x*w.x + w.y*w.y + w.z*w.z + w.w*w.w;
    }
    Esq[k] = s;
}

// ---------------- VQ: per-scalar transform -> argmin over 512 codes ----------
// one thread per (b,d). Zero LDS, zero barriers. e[64] held in 16 NAMED float4
// registers (e0..e15) so the allocator cannot demote it to scratch (round-1
// lesson: VGPR_Count=52 + WRITE_SIZE bloat = e[] spilled, latency-bound).
// __launch_bounds__(256,4) caps VGPRs at 128 (fits) while keeping 16 waves/CU.
// Distance arithmetic is expression-identical to the passing kernel ->
// identical argmin bits -> identical outputs.
#define FOR16(X) X(0) X(1) X(2) X(3) X(4) X(5) X(6) X(7) \
                 X(8) X(9) X(10) X(11) X(12) X(13) X(14) X(15)

__global__ __launch_bounds__(256, 4) void vq_k(
    const float* __restrict__ zencf, const float* __restrict__ Wt1,
    const float* __restrict__ bt1, const float* __restrict__ Wt2,
    const float* __restrict__ bt2, const float* __restrict__ E,
    const float* __restrict__ Esq,
    float* __restrict__ qout, float* __restrict__ sumsq, float* __restrict__ counts)
{
    const int tid = threadIdx.x;
    const int gid = blockIdx.x*256 + tid;
    const float z = zencf[gid];

    // ---- e = bt2 + sum_i relu(z*Wt1[i]+bt1[i]) * Wt2[i,:] (named regs) ----
    const float4* b2 = (const float4*)bt2;
#define EDECL(m) float4 e##m = b2[m];
    FOR16(EDECL)
#undef EDECL

    for (int i = 0; i < 32; i++) {
        float a = fmaxf(z*Wt1[i] + bt1[i], 0.f);
        const float4* wrow = (const float4*)(Wt2 + i*64);
#define TSTEP(m) { float4 w = wrow[m]; \
        e##m.x += a*w.x; e##m.y += a*w.y; e##m.z += a*w.z; e##m.w += a*w.w; }
        FOR16(TSTEP)
#undef TSTEP
    }

    // ---- argmin_k  Esq[k] - 2*dot(e, E[k])  (first-min tie break) ----
    float best = 3.4e38f; int bi = 0;
    #pragma unroll 2
    for (int k = 0; k < 512; k++) {
        const float4* row = (const float4*)(E + (size_t)k*64);
        float d0=0.f, d1=0.f, d2=0.f, d3=0.f;
#define DSTEP(m) { float4 w = row[m]; \
        d0 += e##m.x*w.x; d1 += e##m.y*w.y; d2 += e##m.z*w.z; d3 += e##m.w*w.w; }
        FOR16(DSTEP)
#undef DSTEP
        float s = Esq[k] - 2.f*((d0+d1)+(d2+d3));
        if (s < best) { best = s; bi = k; }
    }

    // ---- q = E[bi] exact f32 copy; local (q-e)^2 sum; histogram ----
    float ls = 0.f;
    const float4* Eq4 = (const float4*)(E + (size_t)bi*64);
    float2* qo2 = (float2*)(qout + (size_t)gid*64);   // 8B-aligned (base %16 == 8)
#define QSTEP(m) { float4 w = Eq4[m]; \
        qo2[2*m+0] = make_float2(w.x, w.y); \
        qo2[2*m+1] = make_float2(w.z, w.w); \
        float d; \
        d = w.x - e##m.x; ls += d*d; \
        d = w.y - e##m.y; ls += d*d; \
        d = w.z - e##m.z; ls += d*d; \
        d = w.w - e##m.w; ls += d*d; }
    FOR16(QSTEP)
#undef QSTEP
    atomicAdd(&counts[bi], 1.f);
    #pragma unroll
    for (int off = 32; off > 0; off >>= 1)
        ls += __shfl_down(ls, off, 64);
    if ((tid & 63) == 0) atomicAdd(sumsq, ls);
}

// ---------------- losses / perplexity ---------------------------------------
__global__ __launch_bounds__(512) void finalize_k(
    const float* __restrict__ sumsq, const float* __restrict__ counts,
    float* __restrict__ out)
{
    __shared__ float red[512];
    int tid = threadIdx.x;
    float p = counts[tid] * (1.f/262144.f);
    red[tid] = p * logf(p + 1e-10f);
    __syncthreads();
    for (int s = 256; s > 0; s >>= 1) { if (tid < s) red[tid] += red[tid+s]; __syncthreads(); }
    if (tid == 0) {
        out[0]       = 1.25f * sumsq[0] * (1.f/16777216.f); // vq_loss = (1+0.25)*mse
        out[2097153] = expf(-red[0]);                        // perplexity
    }
}

extern "C" void kernel_launch(void* const* d_in, const int* in_sizes, int n_in,
                              void* d_out, int out_size, void* d_ws, size_t ws_size,
                              hipStream_t stream)
{
    // Reference dtypes are float32 throughout -> all inputs/outputs are f32.
    const float* x    = (const float*)d_in[0];
    const float* We1  = (const float*)d_in[1];  const float* be1  = (const float*)d_in[2];
    const float* We2  = (const float*)d_in[3];  const float* be2  = (const float*)d_in[4];
    const float* Wre1 = (const float*)d_in[5];  const float* bre1 = (const float*)d_in[6];
    const float* Wre2 = (const float*)d_in[7];  const float* bre2 = (const float*)d_in[8];
    const float* ge   = (const float*)d_in[9];  const float* bebn = (const float*)d_in[10];
    const float* E    = (const float*)d_in[11];
    const float* Wt1  = (const float*)d_in[12]; const float* bt1  = (const float*)d_in[13];
    const float* Wt2  = (const float*)d_in[14]; const float* bt2  = (const float*)d_in[15];
    const float* Wc   = (const float*)d_in[16]; const float* bc   = (const float*)d_in[17];
    const float* Wp   = (const float*)d_in[18]; const float* bp   = (const float*)d_in[19];
    const float* Wrd1 = (const float*)d_in[20]; const float* brd1 = (const float*)d_in[21];
    const float* Wrd2 = (const float*)d_in[22]; const float* brd2 = (const float*)d_in[23];
    const float* gd   = (const float*)d_in[24]; const float* bdbn = (const float*)d_in[25];
    const float* Wd1  = (const float*)d_in[26]; const float* bd1  = (const float*)d_in[27];
    const float* Wd2  = (const float*)d_in[28]; const float* bd2  = (const float*)d_in[29];

    // f32 output, flat: vq_loss[1] | x_recon[2097152] | ppl[1] | q_st[16777216]
    //                  | cls[5120] | zenc[262144]
    float* out    = (float*)d_out;
    float* o_xr   = out + 1;
    float* o_q    = out + 2097154;
    float* o_cls  = out + 18874370;
    float* o_zenc = out + 18879490;

    // ws (floats): small zeroed buffers first; total ~8.5 MB.
    float* ws    = (float*)d_ws;
    float* sumsq = ws + 0;        // 1      [zeroed]
    float* cnts  = ws + 16;       // 512    [zeroed]
    float* t1    = ws + 528;      // 8192   [zeroed]
    float* t2    = ws + 8720;     // 8192   [zeroed]
    float* clsf  = ws + 16912;    // 5120   [zeroed]
    float* z0    = ws + 22032;    // 262144 [zeroed]
    float* dp0   = ws + 284176;   // 262144 [zeroed]
    float* zencf = ws + 546320;   // 262144
    float* dd    = ws + 808464;   // 262144
    float* hbuf  = ws + 1070608;  // 1048576 (dead before d2 -> d2 reuses)
    float* d2    = ws + 1070608;
    float* esq   = ws + 1070608;  // 512 (aliases hbuf: dead after We2 gemm,
                                  //      overwritten again only by d2 later)

    dim3 blk(16, 16);

    zero_k<<<dim3(2135), dim3(256), 0, stream>>>(ws, 546320);

    // ---- encoder ----
    gemm_fused<ACT_RELU><<<dim3(32, 8), blk, 0, stream>>>(
        x, We1, be1, hbuf, nullptr, nullptr, nullptr, nullptr, 512, 2048, 4096);
    gemm_acc<<<dim3(8, 8, 4), blk, 0, stream>>>(hbuf, We2, z0, 512, 512, 2048, 512);
    epi_k<ACT_RELU><<<dim3(1024), dim3(256), 0, stream>>>(z0, be2, nullptr, 512, 512);
    gemm_acc<<<dim3(1, 8, 32), blk, 0, stream>>>(z0, Wre1, t1, 512, 16, 512, 16);
    epi_k<ACT_RELU><<<dim3(32), dim3(256), 0, stream>>>(t1, bre1, nullptr, 512, 16);
    gemm_fused<ACT_RESBN><<<dim3(8, 8), blk, 0, stream>>>(
        t1, Wre2, bre2, zencf, o_zenc, z0, ge, bebn, 512, 512, 16);

    // ---- vector quantizer ----
    esq_k<<<dim3(2), dim3(256), 0, stream>>>(E, esq);
    vq_k<<<dim3(1024), dim3(256), 0, stream>>>(zencf, Wt1, bt1, Wt2, bt2, E, esq,
                                               o_q, sumsq, cnts);
    finalize_k<<<dim3(1), dim3(512), 0, stream>>>(sumsq, cnts, out);

    // ---- classifier head ----
    gemm_acc<<<dim3(1, 8, 32), blk, 0, stream>>>(o_q, Wc, clsf, 512, 10, 32768, 1024);
    epi_k<ACT_SIGMOID><<<dim3(20), dim3(256), 0, stream>>>(clsf, bc, o_cls, 512, 10);

    // ---- decoder ----
    gemm_acc<<<dim3(8, 8, 8), blk, 0, stream>>>(o_q, Wp, dp0, 512, 512, 32768, 4096);
    epi_k<ACT_RELU><<<dim3(1024), dim3(256), 0, stream>>>(dp0, bp, nullptr, 512, 512);
    gemm_acc<<<dim3(1, 8, 32), blk, 0, stream>>>(dp0, Wrd1, t2, 512, 16, 512, 16);
    epi_k<ACT_RELU><<<dim3(32), dim3(256), 0, stream>>>(t2, brd1, nullptr, 512, 16);
    gemm_fused<ACT_RESBN><<<dim3(8, 8), blk, 0, stream>>>(
        t2, Wrd2, brd2, dd, nullptr, dp0, gd, bdbn, 512, 512, 16);
    gemm_fused<ACT_RELU><<<dim3(32, 8), blk, 0, stream>>>(
        dd, Wd1, bd1, d2, nullptr, nullptr, nullptr, nullptr, 512, 2048, 512);
    gemm_fused<ACT_RELU><<<dim3(64, 8), blk, 0, stream>>>(
        d2, Wd2, bd2, o_xr, nullptr, nullptr, nullptr, nullptr, 512, 4096, 2048);
}

// Round 3
// 4780.601 us; speedup vs baseline: 1.0030x; 1.0030x over previous
//
#include <hip/hip_runtime.h>

typedef unsigned int uint;

enum { ACT_RELU=0, ACT_SIGMOID=1, ACT_RESBN=2 };

// ---------------- fused GEMM (f32): C = act(A @ W + bias) [+BN/residual] -----
// A:[M,K] row-major, W:[K,N] row-major. Optional second store C2 (same values).
// tile 64x64, BK=16, 256 threads, 4x4 acc/thread. M%64==0, K%16==0.
template<int ACT>
__global__ __launch_bounds__(256) void gemm_fused(
    const float* __restrict__ A, const float* __restrict__ W,
    const float* __restrict__ bias, float* __restrict__ C,
    float* __restrict__ C2, const float* __restrict__ R,
    const float* __restrict__ gamma, const float* __restrict__ beta,
    int M, int N, int K)
{
    __shared__ float As[16][68];
    __shared__ float Bs[16][68];
    const int tx = threadIdx.x, ty = threadIdx.y;
    const int tid = ty*16 + tx;
    const int row0 = blockIdx.y*64, col0 = blockIdx.x*64;
    float acc[4][4] = {};
    for (int k0 = 0; k0 < K; k0 += 16) {
        #pragma unroll
        for (int t = tid; t < 1024; t += 256) {
            int r = t >> 4, c = t & 15;
            As[c][r] = A[(size_t)(row0+r)*K + k0 + c];
        }
        #pragma unroll
        for (int t = tid; t < 1024; t += 256) {
            int kr = t >> 6, c = t & 63;
            int gc = col0 + c;
            Bs[kr][c] = (gc < N) ? W[(size_t)(k0+kr)*N + gc] : 0.f;
        }
        __syncthreads();
        #pragma unroll
        for (int kk = 0; kk < 16; kk++) {
            float a[4], b[4];
            #pragma unroll
            for (int i = 0; i < 4; i++) a[i] = As[kk][ty*4+i];
            #pragma unroll
            for (int j = 0; j < 4; j++) b[j] = Bs[kk][tx*4+j];
            #pragma unroll
            for (int i = 0; i < 4; i++)
                #pragma unroll
                for (int j = 0; j < 4; j++)
                    acc[i][j] += a[i]*b[j];
        }
        __syncthreads();
    }
    const float INVS = 0.99999500003749968f; // 1/sqrt(1+1e-5)
    #pragma unroll
    for (int i = 0; i < 4; i++) {
        int r = row0 + ty*4 + i;
        #pragma unroll
        for (int j = 0; j < 4; j++) {
            int c = col0 + tx*4 + j;
            if (c < N) {
                float v = acc[i][j] + bias[c];
                if (ACT == ACT_RELU) {
                    v = fmaxf(v, 0.f);
                } else if (ACT == ACT_SIGMOID) {
                    v = 1.f/(1.f + expf(-v));
                } else { // RESBN: relu -> *gamma/sqrt(1+eps)+beta -> +R
                    v = fmaxf(v, 0.f);
                    v = v*(gamma[c]*INVS) + beta[c];
                    v += R[(size_t)r*N + c];
                }
                C[(size_t)r*N + c] = v;
                if (C2) C2[(size_t)r*N + c] = v;
            }
        }
    }
}

// ---------------- split-K accumulating GEMM: C += A@W chunk ------------------
__global__ __launch_bounds__(256) void gemm_acc(
    const float* __restrict__ A, const float* __restrict__ W,
    float* __restrict__ C, int M, int N, int K, int kchunk)
{
    __shared__ float As[16][68];
    __shared__ float Bs[16][68];
    const int tx = threadIdx.x, ty = threadIdx.y;
    const int tid = ty*16 + tx;
    const int row0 = blockIdx.y*64, col0 = blockIdx.x*64;
    const int kbeg = blockIdx.z * kchunk, kend = kbeg + kchunk;
    float acc[4][4] = {};
    for (int k0 = kbeg; k0 < kend; k0 += 16) {
        #pragma unroll
        for (int t = tid; t < 1024; t += 256) {
            int r = t >> 4, c = t & 15;
            As[c][r] = A[(size_t)(row0+r)*K + k0 + c];
        }
        #pragma unroll
        for (int t = tid; t < 1024; t += 256) {
            int kr = t >> 6, c = t & 63;
            int gc = col0 + c;
            Bs[kr][c] = (gc < N) ? W[(size_t)(k0+kr)*N + gc] : 0.f;
        }
        __syncthreads();
        #pragma unroll
        for (int kk = 0; kk < 16; kk++) {
            float a[4], b[4];
            #pragma unroll
            for (int i = 0; i < 4; i++) a[i] = As[kk][ty*4+i];
            #pragma unroll
            for (int j = 0; j < 4; j++) b[j] = Bs[kk][tx*4+j];
            #pragma unroll
            for (int i = 0; i < 4; i++)
                #pragma unroll
                for (int j = 0; j < 4; j++)
                    acc[i][j] += a[i]*b[j];
        }
        __syncthreads();
    }
    #pragma unroll
    for (int i = 0; i < 4; i++) {
        int r = row0 + ty*4 + i;
        #pragma unroll
        for (int j = 0; j < 4; j++) {
            int c = col0 + tx*4 + j;
            if (c < N) atomicAdd(&C[(size_t)r*N + c], acc[i][j]);
        }
    }
}

// ---------------- epilogue for split-K results -------------------------------
template<int ACT>
__global__ __launch_bounds__(256) void epi_k(
    float* __restrict__ C, const float* __restrict__ bias,
    float* __restrict__ dst, int M, int N)
{
    int i = blockIdx.x*256 + threadIdx.x;
    if (i >= M*N) return;
    int c = i % N;
    float v = C[i] + bias[c];
    if (ACT == ACT_RELU) v = fmaxf(v, 0.f);
    else v = 1.f/(1.f + expf(-v));
    C[i] = v;
    if (dst) dst[i] = v;
}

__global__ __launch_bounds__(256) void zero_k(float* __restrict__ p, int n)
{
    int i = blockIdx.x*256 + threadIdx.x;
    if (i < n) p[i] = 0.f;
}

// ---------------- Esq: per-code squared norms (bitwise-same accum order) -----
__global__ __launch_bounds__(256) void esq_k(
    const float* __restrict__ E, float* __restrict__ Esq)
{
    int k = blockIdx.x*256 + threadIdx.x;
    if (k >= 512) return;
    const float4* row = (const float4*)(E + (size_t)k*64);
    float s = 0.f;
    #pragma unroll
    for (int m = 0; m < 16; m++) {
        float4 w = row[m];
        s += w.x*w.x + w.y*w.y + w.z*w.z + w.w*w.w;
    }
    Esq[k] = s;
}

// ---------------- VQ: per-scalar transform -> argmin over 512 codes ----------
// one thread per (b,d). Zero LDS, zero barriers. Round-1/2 lesson: the e[64]
// state spilled to scratch (VGPR_Count=52, WRITE_SIZE +50MB) because (a)
// unroll-2 kept TWO full E-rows (128 VGPRs) live and (b) launch_bounds' 2nd
// arg only sets a MIN waves/EU -- the scheduler still targeted 8 waves/EU
// (64-VGPR budget) and spilled e to meet it. Fix: no unroll; process rows in
// 8-float4 half-chunks (<=32 row VGPRs live); amdgpu_waves_per_eu(4,4) pins
// the pressure target at 128 VGPRs. Accumulation order per d0..d3 is
// element-for-element identical to the passing kernel -> identical argmin.
#define FOR8A(X) X(0) X(1) X(2) X(3) X(4) X(5) X(6) X(7)
#define FOR8B(X) X(8) X(9) X(10) X(11) X(12) X(13) X(14) X(15)
#define FOR16(X) FOR8A(X) FOR8B(X)

__global__ __launch_bounds__(256)
__attribute__((amdgpu_waves_per_eu(4, 4)))
void vq_k(
    const float* __restrict__ zencf, const float* __restrict__ Wt1,
    const float* __restrict__ bt1, const float* __restrict__ Wt2,
    const float* __restrict__ bt2, const float* __restrict__ E,
    const float* __restrict__ Esq,
    float* __restrict__ qout, float* __restrict__ sumsq, float* __restrict__ counts)
{
    const int tid = threadIdx.x;
    const int gid = blockIdx.x*256 + tid;
    const float z = zencf[gid];

    // ---- e = bt2 + sum_i relu(z*Wt1[i]+bt1[i]) * Wt2[i,:] (named regs) ----
    const float4* b2 = (const float4*)bt2;
#define EDECL(m) float4 e##m = b2[m];
    FOR16(EDECL)
#undef EDECL

    for (int i = 0; i < 32; i++) {
        float a = fmaxf(z*Wt1[i] + bt1[i], 0.f);
        const float4* wrow = (const float4*)(Wt2 + i*64);
#define TSTEP(m) { float4 w = wrow[m]; \
        e##m.x += a*w.x; e##m.y += a*w.y; e##m.z += a*w.z; e##m.w += a*w.w; }
        FOR8A(TSTEP)
        FOR8B(TSTEP)
#undef TSTEP
    }

    // ---- argmin_k  Esq[k] - 2*dot(e, E[k])  (first-min tie break) ----
    float best = 3.4e38f; int bi = 0;
    for (int k = 0; k < 512; k++) {
        const float4* row = (const float4*)(E + (size_t)k*64);
        float d0=0.f, d1=0.f, d2=0.f, d3=0.f;
        // half A: m=0..7 loaded then consumed (<=32 row VGPRs live)
#define LOADW(m) float4 w##m = row[m];
#define DOTW(m)  d0 += e##m.x*w##m.x; d1 += e##m.y*w##m.y; \
                 d2 += e##m.z*w##m.z; d3 += e##m.w*w##m.w;
        FOR8A(LOADW)
        FOR8A(DOTW)
        // half B: m=8..15
        FOR8B(LOADW)
        FOR8B(DOTW)
#undef LOADW
#undef DOTW
        float s = Esq[k] - 2.f*((d0+d1)+(d2+d3));
        if (s < best) { best = s; bi = k; }
    }

    // ---- q = E[bi] exact f32 copy; local (q-e)^2 sum; histogram ----
    float ls = 0.f;
    const float4* Eq4 = (const float4*)(E + (size_t)bi*64);
    float2* qo2 = (float2*)(qout + (size_t)gid*64);   // 8B-aligned (base %16 == 8)
#define QSTEP(m) { float4 w = Eq4[m]; \
        qo2[2*m+0] = make_float2(w.x, w.y); \
        qo2[2*m+1] = make_float2(w.z, w.w); \
        float d; \
        d = w.x - e##m.x; ls += d*d; \
        d = w.y - e##m.y; ls += d*d; \
        d = w.z - e##m.z; ls += d*d; \
        d = w.w - e##m.w; ls += d*d; }
    FOR16(QSTEP)
#undef QSTEP
    atomicAdd(&counts[bi], 1.f);
    #pragma unroll
    for (int off = 32; off > 0; off >>= 1)
        ls += __shfl_down(ls, off, 64);
    if ((tid & 63) == 0) atomicAdd(sumsq, ls);
}

// ---------------- losses / perplexity ---------------------------------------
__global__ __launch_bounds__(512) void finalize_k(
    const float* __restrict__ sumsq, const float* __restrict__ counts,
    float* __restrict__ out)
{
    __shared__ float red[512];
    int tid = threadIdx.x;
    float p = counts[tid] * (1.f/262144.f);
    red[tid] = p * logf(p + 1e-10f);
    __syncthreads();
    for (int s = 256; s > 0; s >>= 1) { if (tid < s) red[tid] += red[tid+s]; __syncthreads(); }
    if (tid == 0) {
        out[0]       = 1.25f * sumsq[0] * (1.f/16777216.f); // vq_loss = (1+0.25)*mse
        out[2097153] = expf(-red[0]);                        // perplexity
    }
}

extern "C" void kernel_launch(void* const* d_in, const int* in_sizes, int n_in,
                              void* d_out, int out_size, void* d_ws, size_t ws_size,
                              hipStream_t stream)
{
    // Reference dtypes are float32 throughout -> all inputs/outputs are f32.
    const float* x    = (const float*)d_in[0];
    const float* We1  = (const float*)d_in[1];  const float* be1  = (const float*)d_in[2];
    const float* We2  = (const float*)d_in[3];  const float* be2  = (const float*)d_in[4];
    const float* Wre1 = (const float*)d_in[5];  const float* bre1 = (const float*)d_in[6];
    const float* Wre2 = (const float*)d_in[7];  const float* bre2 = (const float*)d_in[8];
    const float* ge   = (const float*)d_in[9];  const float* bebn = (const float*)d_in[10];
    const float* E    = (const float*)d_in[11];
    const float* Wt1  = (const float*)d_in[12]; const float* bt1  = (const float*)d_in[13];
    const float* Wt2  = (const float*)d_in[14]; const float* bt2  = (const float*)d_in[15];
    const float* Wc   = (const float*)d_in[16]; const float* bc   = (const float*)d_in[17];
    const float* Wp   = (const float*)d_in[18]; const float* bp   = (const float*)d_in[19];
    const float* Wrd1 = (const float*)d_in[20]; const float* brd1 = (const float*)d_in[21];
    const float* Wrd2 = (const float*)d_in[22]; const float* brd2 = (const float*)d_in[23];
    const float* gd   = (const float*)d_in[24]; const float* bdbn = (const float*)d_in[25];
    const float* Wd1  = (const float*)d_in[26]; const float* bd1  = (const float*)d_in[27];
    const float* Wd2  = (const float*)d_in[28]; const float* bd2  = (const float*)d_in[29];

    // f32 output, flat: vq_loss[1] | x_recon[2097152] | ppl[1] | q_st[16777216]
    //                  | cls[5120] | zenc[262144]
    float* out    = (float*)d_out;
    float* o_xr   = out + 1;
    float* o_q    = out + 2097154;
    float* o_cls  = out + 18874370;
    float* o_zenc = out + 18879490;

    // ws (floats): small zeroed buffers first; total ~8.5 MB.
    float* ws    = (float*)d_ws;
    float* sumsq = ws + 0;        // 1      [zeroed]
    float* cnts  = ws + 16;       // 512    [zeroed]
    float* t1    = ws + 528;      // 8192   [zeroed]
    float* t2    = ws + 8720;     // 8192   [zeroed]
    float* clsf  = ws + 16912;    // 5120   [zeroed]
    float* z0    = ws + 22032;    // 262144 [zeroed]
    float* dp0   = ws + 284176;   // 262144 [zeroed]
    float* zencf = ws + 546320;   // 262144
    float* dd    = ws + 808464;   // 262144
    float* hbuf  = ws + 1070608;  // 1048576 (dead before d2 -> d2 reuses)
    float* d2    = ws + 1070608;
    float* esq   = ws + 1070608;  // 512 (aliases hbuf: dead after We2 gemm,
                                  //      overwritten again only by d2 later)

    dim3 blk(16, 16);

    zero_k<<<dim3(2135), dim3(256), 0, stream>>>(ws, 546320);

    // ---- encoder ----
    gemm_fused<ACT_RELU><<<dim3(32, 8), blk, 0, stream>>>(
        x, We1, be1, hbuf, nullptr, nullptr, nullptr, nullptr, 512, 2048, 4096);
    gemm_acc<<<dim3(8, 8, 4), blk, 0, stream>>>(hbuf, We2, z0, 512, 512, 2048, 512);
    epi_k<ACT_RELU><<<dim3(1024), dim3(256), 0, stream>>>(z0, be2, nullptr, 512, 512);
    gemm_acc<<<dim3(1, 8, 32), blk, 0, stream>>>(z0, Wre1, t1, 512, 16, 512, 16);
    epi_k<ACT_RELU><<<dim3(32), dim3(256), 0, stream>>>(t1, bre1, nullptr, 512, 16);
    gemm_fused<ACT_RESBN><<<dim3(8, 8), blk, 0, stream>>>(
        t1, Wre2, bre2, zencf, o_zenc, z0, ge, bebn, 512, 512, 16);

    // ---- vector quantizer ----
    esq_k<<<dim3(2), dim3(256), 0, stream>>>(E, esq);
    vq_k<<<dim3(1024), dim3(256), 0, stream>>>(zencf, Wt1, bt1, Wt2, bt2, E, esq,
                                               o_q, sumsq, cnts);
    finalize_k<<<dim3(1), dim3(512), 0, stream>>>(sumsq, cnts, out);

    // ---- classifier head ----
    gemm_acc<<<dim3(1, 8, 32), blk, 0, stream>>>(o_q, Wc, clsf, 512, 10, 32768, 1024);
    epi_k<ACT_SIGMOID><<<dim3(20), dim3(256), 0, stream>>>(clsf, bc, o_cls, 512, 10);

    // ---- decoder ----
    gemm_acc<<<dim3(8, 8, 8), blk, 0, stream>>>(o_q, Wp, dp0, 512, 512, 32768, 4096);
    epi_k<ACT_RELU><<<dim3(1024), dim3(256), 0, stream>>>(dp0, bp, nullptr, 512, 512);
    gemm_acc<<<dim3(1, 8, 32), blk, 0, stream>>>(dp0, Wrd1, t2, 512, 16, 512, 16);
    epi_k<ACT_RELU><<<dim3(32), dim3(256), 0, stream>>>(t2, brd1, nullptr, 512, 16);
    gemm_fused<ACT_RESBN><<<dim3(8, 8), blk, 0, stream>>>(
        t2, Wrd2, brd2, dd, nullptr, dp0, gd, bdbn, 512, 512, 16);
    gemm_fused<ACT_RELU><<<dim3(32, 8), blk, 0, stream>>>(
        dd, Wd1, bd1, d2, nullptr, nullptr, nullptr, nullptr, 512, 2048, 512);
    gemm_fused<ACT_RELU><<<dim3(64, 8), blk, 0, stream>>>(
        d2, Wd2, bd2, o_xr, nullptr, nullptr, nullptr, nullptr, 512, 4096, 2048);
}

// Round 4
// 4619.608 us; speedup vs baseline: 1.0380x; 1.0348x over previous
//
#include <hip/hip_runtime.h>

typedef unsigned int uint;

enum { ACT_RELU=0, ACT_SIGMOID=1, ACT_RESBN=2 };

// ---------------- fused GEMM (f32): C = act(A @ W + bias) [+BN/residual] -----
// A:[M,K] row-major, W:[K,N] row-major. Optional second store C2 (same values).
// tile 64x64, BK=16, 256 threads, 4x4 acc/thread. M%64==0, K%16==0.
template<int ACT>
__global__ __launch_bounds__(256) void gemm_fused(
    const float* __restrict__ A, const float* __restrict__ W,
    const float* __restrict__ bias, float* __restrict__ C,
    float* __restrict__ C2, const float* __restrict__ R,
    const float* __restrict__ gamma, const float* __restrict__ beta,
    int M, int N, int K)
{
    __shared__ float As[16][68];
    __shared__ float Bs[16][68];
    const int tx = threadIdx.x, ty = threadIdx.y;
    const int tid = ty*16 + tx;
    const int row0 = blockIdx.y*64, col0 = blockIdx.x*64;
    float acc[4][4] = {};
    for (int k0 = 0; k0 < K; k0 += 16) {
        #pragma unroll
        for (int t = tid; t < 1024; t += 256) {
            int r = t >> 4, c = t & 15;
            As[c][r] = A[(size_t)(row0+r)*K + k0 + c];
        }
        #pragma unroll
        for (int t = tid; t < 1024; t += 256) {
            int kr = t >> 6, c = t & 63;
            int gc = col0 + c;
            Bs[kr][c] = (gc < N) ? W[(size_t)(k0+kr)*N + gc] : 0.f;
        }
        __syncthreads();
        #pragma unroll
        for (int kk = 0; kk < 16; kk++) {
            float a[4], b[4];
            #pragma unroll
            for (int i = 0; i < 4; i++) a[i] = As[kk][ty*4+i];
            #pragma unroll
            for (int j = 0; j < 4; j++) b[j] = Bs[kk][tx*4+j];
            #pragma unroll
            for (int i = 0; i < 4; i++)
                #pragma unroll
                for (int j = 0; j < 4; j++)
                    acc[i][j] += a[i]*b[j];
        }
        __syncthreads();
    }
    const float INVS = 0.99999500003749968f; // 1/sqrt(1+1e-5)
    #pragma unroll
    for (int i = 0; i < 4; i++) {
        int r = row0 + ty*4 + i;
        #pragma unroll
        for (int j = 0; j < 4; j++) {
            int c = col0 + tx*4 + j;
            if (c < N) {
                float v = acc[i][j] + bias[c];
                if (ACT == ACT_RELU) {
                    v = fmaxf(v, 0.f);
                } else if (ACT == ACT_SIGMOID) {
                    v = 1.f/(1.f + expf(-v));
                } else { // RESBN: relu -> *gamma/sqrt(1+eps)+beta -> +R
                    v = fmaxf(v, 0.f);
                    v = v*(gamma[c]*INVS) + beta[c];
                    v += R[(size_t)r*N + c];
                }
                C[(size_t)r*N + c] = v;
                if (C2) C2[(size_t)r*N + c] = v;
            }
        }
    }
}

// ---------------- split-K accumulating GEMM: C += A@W chunk ------------------
__global__ __launch_bounds__(256) void gemm_acc(
    const float* __restrict__ A, const float* __restrict__ W,
    float* __restrict__ C, int M, int N, int K, int kchunk)
{
    __shared__ float As[16][68];
    __shared__ float Bs[16][68];
    const int tx = threadIdx.x, ty = threadIdx.y;
    const int tid = ty*16 + tx;
    const int row0 = blockIdx.y*64, col0 = blockIdx.x*64;
    const int kbeg = blockIdx.z * kchunk, kend = kbeg + kchunk;
    float acc[4][4] = {};
    for (int k0 = kbeg; k0 < kend; k0 += 16) {
        #pragma unroll
        for (int t = tid; t < 1024; t += 256) {
            int r = t >> 4, c = t & 15;
            As[c][r] = A[(size_t)(row0+r)*K + k0 + c];
        }
        #pragma unroll
        for (int t = tid; t < 1024; t += 256) {
            int kr = t >> 6, c = t & 63;
            int gc = col0 + c;
            Bs[kr][c] = (gc < N) ? W[(size_t)(k0+kr)*N + gc] : 0.f;
        }
        __syncthreads();
        #pragma unroll
        for (int kk = 0; kk < 16; kk++) {
            float a[4], b[4];
            #pragma unroll
            for (int i = 0; i < 4; i++) a[i] = As[kk][ty*4+i];
            #pragma unroll
            for (int j = 0; j < 4; j++) b[j] = Bs[kk][tx*4+j];
            #pragma unroll
            for (int i = 0; i < 4; i++)
                #pragma unroll
                for (int j = 0; j < 4; j++)
                    acc[i][j] += a[i]*b[j];
        }
        __syncthreads();
    }
    #pragma unroll
    for (int i = 0; i < 4; i++) {
        int r = row0 + ty*4 + i;
        #pragma unroll
        for (int j = 0; j < 4; j++) {
            int c = col0 + tx*4 + j;
            if (c < N) atomicAdd(&C[(size_t)r*N + c], acc[i][j]);
        }
    }
}

// ---------------- epilogue for split-K results -------------------------------
template<int ACT>
__global__ __launch_bounds__(256) void epi_k(
    float* __restrict__ C, const float* __restrict__ bias,
    float* __restrict__ dst, int M, int N)
{
    int i = blockIdx.x*256 + threadIdx.x;
    if (i >= M*N) return;
    int c = i % N;
    float v = C[i] + bias[c];
    if (ACT == ACT_RELU) v = fmaxf(v, 0.f);
    else v = 1.f/(1.f + expf(-v));
    C[i] = v;
    if (dst) dst[i] = v;
}

__global__ __launch_bounds__(256) void zero_k(float* __restrict__ p, int n)
{
    int i = blockIdx.x*256 + threadIdx.x;
    if (i < n) p[i] = 0.f;
}

// ---------------- Esq: per-code squared norms --------------------------------
__global__ __launch_bounds__(256) void esq_k(
    const float* __restrict__ E, float* __restrict__ Esq)
{
    int k = blockIdx.x*256 + threadIdx.x;
    if (k >= 512) return;
    const float4* row = (const float4*)(E + (size_t)k*64);
    float s = 0.f;
    #pragma unroll
    for (int m = 0; m < 16; m++) {
        float4 w = row[m];
        s += w.x*w.x + w.y*w.y + w.z*w.z + w.w*w.w;
    }
    Esq[k] = s;
}

// ---------------- VQ: tiled distance-GEMM + fused argmin ---------------------
// Rounds 1-3 lesson: "one thread owns e[64], streams all 512 E rows" spills
// its 64-reg state to scratch no matter what (VGPR 52/64, +35MB scratch
// traffic, VALUBusy 6%, invariant 2.27ms). This is a [262144x64]*[64x512]
// GEMM -- tile it like one. Block = 64 rows x 512 codes (4 code-tiles of
// 128). e-tile [64x64] computed straight into LDS (transposed); E tiles
// staged transposed; thread = 4 rows x 8 codes, acc[4][8] (32 regs -- the
// pressure class the existing gemm kernels handle without spill). Inner
// loop: 3 x ds_read_b128 per 32 FMA. Argmin: per-thread first-min over an
// ascending code set, cross-thread LDS reduce with (s, then lower index)
// tie-break == np.argmin first-min semantics.
__global__ __launch_bounds__(256) void vqdist_k(
    const float* __restrict__ zencf, const float* __restrict__ Wt1,
    const float* __restrict__ bt1, const float* __restrict__ Wt2,
    const float* __restrict__ bt2, const float* __restrict__ E,
    const float* __restrict__ Esq,
    float* __restrict__ qout, float* __restrict__ sumsq, float* __restrict__ counts)
{
    __shared__ float Es_t[64][72];    // [dim][row]  e-tile, transposed
    __shared__ float Bs_t[64][132];   // [dim][code] E-tile, transposed (128 codes)
    __shared__ float Esqs[512];
    __shared__ int   rowbi[64];
    __shared__ float red[256];
    // bsS/bsI alias Bs_t (dead after last code-tile): 64x16 f32 + 64x16 i32
    float (*bsS)[16] = (float (*)[16])(&Bs_t[0][0]);   // floats [0,1024)
    int   (*bsI)[16] = (int   (*)[16])(&Bs_t[8][0]);   // floats [1056,2080)

    const int tid = threadIdx.x;
    const int tx = tid & 15, ty = tid >> 4;
    const int row0 = blockIdx.x * 64;

    // ---- e-tile: thread = 1 row x 16 dims; expression identical to ref ----
    {
        const int r  = tid >> 2;          // 0..63
        const int dq = (tid & 3) * 16;    // 0,16,32,48
        const float z = zencf[row0 + r];
        float ev[16];
        const float4* b2 = (const float4*)(bt2 + dq);
        #pragma unroll
        for (int m = 0; m < 4; m++) {
            float4 b = b2[m];
            ev[4*m+0]=b.x; ev[4*m+1]=b.y; ev[4*m+2]=b.z; ev[4*m+3]=b.w;
        }
        for (int i = 0; i < 32; i++) {
            float a = fmaxf(z*Wt1[i] + bt1[i], 0.f);
            const float4* wrow = (const float4*)(Wt2 + i*64 + dq);
            #pragma unroll
            for (int m = 0; m < 4; m++) {
                float4 w = wrow[m];
                ev[4*m+0] += a*w.x; ev[4*m+1] += a*w.y;
                ev[4*m+2] += a*w.z; ev[4*m+3] += a*w.w;
            }
        }
        #pragma unroll
        for (int j = 0; j < 16; j++) Es_t[dq + j][r] = ev[j];
    }
    for (int t = tid; t < 512; t += 256) Esqs[t] = Esq[t];

    float best[4] = {3.4e38f, 3.4e38f, 3.4e38f, 3.4e38f};
    int   bidx[4] = {0, 0, 0, 0};

    for (int ct = 0; ct < 4; ct++) {
        __syncthreads();   // prior tile reads done (also covers e-tile writes)
        {   // stage 128 codes x 64 dims, transposed
            const int c     = tid & 127;
            const int dbase = (tid >> 7) * 32;
            const float4* er = (const float4*)(E + (size_t)(ct*128 + c)*64 + dbase);
            #pragma unroll
            for (int m = 0; m < 8; m++) {
                float4 w = er[m];
                int d = dbase + 4*m;
                Bs_t[d+0][c] = w.x; Bs_t[d+1][c] = w.y;
                Bs_t[d+2][c] = w.z; Bs_t[d+3][c] = w.w;
            }
        }
        __syncthreads();

        float acc[4][8] = {};
        #pragma unroll 8
        for (int kk = 0; kk < 64; kk++) {
            const float4 av = *(const float4*)&Es_t[kk][ty*4];
            const float4 b0 = *(const float4*)&Bs_t[kk][tx*4];
            const float4 b1 = *(const float4*)&Bs_t[kk][64 + tx*4];
            const float a0=av.x, a1=av.y, a2=av.z, a3=av.w;
            const float b[8] = {b0.x,b0.y,b0.z,b0.w, b1.x,b1.y,b1.z,b1.w};
            #pragma unroll
            for (int j = 0; j < 8; j++) {
                acc[0][j] += a0*b[j];
                acc[1][j] += a1*b[j];
                acc[2][j] += a2*b[j];
                acc[3][j] += a3*b[j];
            }
        }
        #pragma unroll
        for (int j = 0; j < 8; j++) {
            const int code = ct*128 + (j < 4 ? tx*4 + j : 64 + tx*4 + (j - 4));
            const float eq = Esqs[code];
            #pragma unroll
            for (int i = 0; i < 4; i++) {
                float s = eq - 2.f*acc[i][j];
                if (s < best[i]) { best[i] = s; bidx[i] = code; }
            }
        }
    }

    __syncthreads();   // Bs_t dead -> safe to alias as bsS/bsI
    #pragma unroll
    for (int i = 0; i < 4; i++) { bsS[ty*4+i][tx] = best[i]; bsI[ty*4+i][tx] = bidx[i]; }
    __syncthreads();
    if (tid < 64) {
        float bs = bsS[tid][0]; int bi = bsI[tid][0];
        #pragma unroll
        for (int t = 1; t < 16; t++) {
            float s = bsS[tid][t]; int ii = bsI[tid][t];
            if (s < bs || (s == bs && ii < bi)) { bs = s; bi = ii; }
        }
        rowbi[tid] = bi;
        atomicAdd(&counts[bi], 1.f);
    }
    __syncthreads();

    // ---- qout = E[bi] exact copy; (q-e)^2 partial; block-reduce sumsq ----
    {
        const int r  = tid >> 2;
        const int dq = (tid & 3) * 16;
        const int bi = rowbi[r];
        const float4* Eq = (const float4*)(E + (size_t)bi*64 + dq);
        float2* qo2 = (float2*)(qout + (size_t)(row0 + r)*64 + dq); // 8B-aligned
        float ls = 0.f;
        #pragma unroll
        for (int m = 0; m < 4; m++) {
            float4 w = Eq[m];
            qo2[2*m+0] = make_float2(w.x, w.y);
            qo2[2*m+1] = make_float2(w.z, w.w);
            float d;
            d = w.x - Es_t[dq+4*m+0][r]; ls += d*d;
            d = w.y - Es_t[dq+4*m+1][r]; ls += d*d;
            d = w.z - Es_t[dq+4*m+2][r]; ls += d*d;
            d = w.w - Es_t[dq+4*m+3][r]; ls += d*d;
        }
        red[tid] = ls;
    }
    __syncthreads();
    for (int s2 = 128; s2 > 0; s2 >>= 1) {
        if (tid < s2) red[tid] += red[tid+s2];
        __syncthreads();
    }
    if (tid == 0) atomicAdd(sumsq, red[0]);
}

// ---------------- losses / perplexity ---------------------------------------
__global__ __launch_bounds__(512) void finalize_k(
    const float* __restrict__ sumsq, const float* __restrict__ counts,
    float* __restrict__ out)
{
    __shared__ float red[512];
    int tid = threadIdx.x;
    float p = counts[tid] * (1.f/262144.f);
    red[tid] = p * logf(p + 1e-10f);
    __syncthreads();
    for (int s = 256; s > 0; s >>= 1) { if (tid < s) red[tid] += red[tid+s]; __syncthreads(); }
    if (tid == 0) {
        out[0]       = 1.25f * sumsq[0] * (1.f/16777216.f); // vq_loss = (1+0.25)*mse
        out[2097153] = expf(-red[0]);                        // perplexity
    }
}

extern "C" void kernel_launch(void* const* d_in, const int* in_sizes, int n_in,
                              void* d_out, int out_size, void* d_ws, size_t ws_size,
                              hipStream_t stream)
{
    // Reference dtypes are float32 throughout -> all inputs/outputs are f32.
    const float* x    = (const float*)d_in[0];
    const float* We1  = (const float*)d_in[1];  const float* be1  = (const float*)d_in[2];
    const float* We2  = (const float*)d_in[3];  const float* be2  = (const float*)d_in[4];
    const float* Wre1 = (const float*)d_in[5];  const float* bre1 = (const float*)d_in[6];
    const float* Wre2 = (const float*)d_in[7];  const float* bre2 = (const float*)d_in[8];
    const float* ge   = (const float*)d_in[9];  const float* bebn = (const float*)d_in[10];
    const float* E    = (const float*)d_in[11];
    const float* Wt1  = (const float*)d_in[12]; const float* bt1  = (const float*)d_in[13];
    const float* Wt2  = (const float*)d_in[14]; const float* bt2  = (const float*)d_in[15];
    const float* Wc   = (const float*)d_in[16]; const float* bc   = (const float*)d_in[17];
    const float* Wp   = (const float*)d_in[18]; const float* bp   = (const float*)d_in[19];
    const float* Wrd1 = (const float*)d_in[20]; const float* brd1 = (const float*)d_in[21];
    const float* Wrd2 = (const float*)d_in[22]; const float* brd2 = (const float*)d_in[23];
    const float* gd   = (const float*)d_in[24]; const float* bdbn = (const float*)d_in[25];
    const float* Wd1  = (const float*)d_in[26]; const float* bd1  = (const float*)d_in[27];
    const float* Wd2  = (const float*)d_in[28]; const float* bd2  = (const float*)d_in[29];

    // f32 output, flat: vq_loss[1] | x_recon[2097152] | ppl[1] | q_st[16777216]
    //                  | cls[5120] | zenc[262144]
    float* out    = (float*)d_out;
    float* o_xr   = out + 1;
    float* o_q    = out + 2097154;
    float* o_cls  = out + 18874370;
    float* o_zenc = out + 18879490;

    // ws (floats): small zeroed buffers first; total ~8.5 MB.
    float* ws    = (float*)d_ws;
    float* sumsq = ws + 0;        // 1      [zeroed]
    float* cnts  = ws + 16;       // 512    [zeroed]
    float* t1    = ws + 528;      // 8192   [zeroed]
    float* t2    = ws + 8720;     // 8192   [zeroed]
    float* clsf  = ws + 16912;    // 5120   [zeroed]
    float* z0    = ws + 22032;    // 262144 [zeroed]
    float* dp0   = ws + 284176;   // 262144 [zeroed]
    float* zencf = ws + 546320;   // 262144
    float* dd    = ws + 808464;   // 262144
    float* hbuf  = ws + 1070608;  // 1048576 (dead before d2 -> d2 reuses)
    float* d2    = ws + 1070608;
    float* esq   = ws + 1070608;  // 512 (aliases hbuf: dead after We2 gemm,
                                  //      overwritten again only by d2 later)

    dim3 blk(16, 16);

    zero_k<<<dim3(2135), dim3(256), 0, stream>>>(ws, 546320);

    // ---- encoder ----
    gemm_fused<ACT_RELU><<<dim3(32, 8), blk, 0, stream>>>(
        x, We1, be1, hbuf, nullptr, nullptr, nullptr, nullptr, 512, 2048, 4096);
    gemm_acc<<<dim3(8, 8, 4), blk, 0, stream>>>(hbuf, We2, z0, 512, 512, 2048, 512);
    epi_k<ACT_RELU><<<dim3(1024), dim3(256), 0, stream>>>(z0, be2, nullptr, 512, 512);
    gemm_acc<<<dim3(1, 8, 32), blk, 0, stream>>>(z0, Wre1, t1, 512, 16, 512, 16);
    epi_k<ACT_RELU><<<dim3(32), dim3(256), 0, stream>>>(t1, bre1, nullptr, 512, 16);
    gemm_fused<ACT_RESBN><<<dim3(8, 8), blk, 0, stream>>>(
        t1, Wre2, bre2, zencf, o_zenc, z0, ge, bebn, 512, 512, 16);

    // ---- vector quantizer ----
    esq_k<<<dim3(2), dim3(256), 0, stream>>>(E, esq);
    vqdist_k<<<dim3(4096), dim3(256), 0, stream>>>(zencf, Wt1, bt1, Wt2, bt2, E, esq,
                                                   o_q, sumsq, cnts);
    finalize_k<<<dim3(1), dim3(512), 0, stream>>>(sumsq, cnts, out);

    // ---- classifier head ----
    gemm_acc<<<dim3(1, 8, 32), blk, 0, stream>>>(o_q, Wc, clsf, 512, 10, 32768, 1024);
    epi_k<ACT_SIGMOID><<<dim3(20), dim3(256), 0, stream>>>(clsf, bc, o_cls, 512, 10);

    // ---- decoder ----
    gemm_acc<<<dim3(8, 8, 8), blk, 0, stream>>>(o_q, Wp, dp0, 512, 512, 32768, 4096);
    epi_k<ACT_RELU><<<dim3(1024), dim3(256), 0, stream>>>(dp0, bp, nullptr, 512, 512);
    gemm_acc<<<dim3(1, 8, 32), blk, 0, stream>>>(dp0, Wrd1, t2, 512, 16, 512, 16);
    epi_k<ACT_RELU><<<dim3(32), dim3(256), 0, stream>>>(t2, brd1, nullptr, 512, 16);
    gemm_fused<ACT_RESBN><<<dim3(8, 8), blk, 0, stream>>>(
        t2, Wrd2, brd2, dd, nullptr, dp0, gd, bdbn, 512, 512, 16);
    gemm_fused<ACT_RELU><<<dim3(32, 8), blk, 0, stream>>>(
        dd, Wd1, bd1, d2, nullptr, nullptr, nullptr, nullptr, 512, 2048, 512);
    gemm_fused<ACT_RELU><<<dim3(64, 8), blk, 0, stream>>>(
        d2, Wd2, bd2, o_xr, nullptr, nullptr, nullptr, nullptr, 512, 4096, 2048);
}